// Round 9
// baseline (403.245 us; speedup 1.0000x reference)
//
#include <hip/hip_runtime.h>
#include <hip/hip_bf16.h>

typedef unsigned short u16;
using short8 = __attribute__((ext_vector_type(8))) short;
using f32x4  = __attribute__((ext_vector_type(4))) float;

#define IN_FEAT  4096
#define OUT_FEAT 4096
#define BATCH    2048
// packed triangular B: group g (128 rows) has row length (g+1)*128 u16;
// group base = 16384 * g*(g+1)/2; total = 16384 * 528 u16 per matrix.
#define BPACK    8650752

// direct global->LDS, 16B per lane; LDS dest is wave-uniform base + lane*16
#define GLOAD16(gp, lp)                                                        \
    __builtin_amdgcn_global_load_lds(                                          \
        (__attribute__((address_space(1))) void*)(gp),                         \
        (__attribute__((address_space(3))) void*)(lp), 16, 0, 0)

// ---------------------------------------------------------------------------
// Kernel 1: split x (f32) into bf16 hi + lo residual. 16B/lane both ways.
// ---------------------------------------------------------------------------
__global__ __launch_bounds__(256) void split_x(const float* __restrict__ x,
                                               u16* __restrict__ xhi,
                                               u16* __restrict__ xlo)
{
    const int n8 = (BATCH * IN_FEAT) / 8;
    for (int i = blockIdx.x * blockDim.x + threadIdx.x; i < n8;
         i += gridDim.x * blockDim.x) {
        float4 a = ((const float4*)x)[2 * i];
        float4 b = ((const float4*)x)[2 * i + 1];
        float vv[8] = {a.x, a.y, a.z, a.w, b.x, b.y, b.z, b.w};
        short8 h, l;
#pragma unroll
        for (int k = 0; k < 8; ++k) {
            __hip_bfloat16 hb = __float2bfloat16(vv[k]);
            float hf = __bfloat162float(hb);
            __hip_bfloat16 lb = __float2bfloat16(vv[k] - hf);
            h[k] = *(short*)&hb;
            l[k] = *(short*)&lb;
        }
        ((short8*)xhi)[i] = h;
        ((short8*)xlo)[i] = l;
    }
}

// ---------------------------------------------------------------------------
// Kernel 2: per output row o (group g = o/128, block r = o/32):
//   Wm = exp(W) on diag block, W on strict-lower; norm over active K;
//   Wn = exp(ls)*Wm/norm -> bf16 hi/lo, packed triangular, zero-padded to
//   kpad=(g+1)*128; log of diag 32x32 block -> jac (separate 32-thread pass).
// ---------------------------------------------------------------------------
__global__ __launch_bounds__(256) void prep_w(const float* __restrict__ W,
                                              const float* __restrict__ wls,
                                              u16* __restrict__ bhi,
                                              u16* __restrict__ blo,
                                              float* __restrict__ jac)
{
    const int o    = 4095 - blockIdx.x;   // heavy rows first (LPT)
    const int r    = o >> 5;              // 32-block row index
    const int g    = o >> 7;              // 128-group index (= GEMM N-tile j)
    const int kact = (r + 1) * 32;        // active K for this row
    const int kpad = (g + 1) << 7;        // packed row length
    const int dlo  = r * 32;              // diag block col start

    __shared__ float rowbuf[4096];
    __shared__ float red[4];

    // pass 1: masked transform + sum of squares (f32x4 in, f32x4 LDS out)
    const float* wrow = W + (size_t)o * IN_FEAT;
    float ss = 0.f;
    const int k4 = kact >> 2;
    for (int c4 = threadIdx.x; c4 < k4; c4 += 256) {
        float4 wv = ((const float4*)wrow)[c4];
        f32x4 out;
        float vv[4] = {wv.x, wv.y, wv.z, wv.w};
        const int c = c4 * 4;
#pragma unroll
        for (int e = 0; e < 4; ++e) {
            float wm = (c + e >= dlo) ? __expf(vv[e]) : vv[e];
            out[e] = wm;
            ss += wm * wm;
        }
        *(f32x4*)&rowbuf[c] = out;
    }
    for (int off = 32; off > 0; off >>= 1) ss += __shfl_down(ss, off, 64);
    const int lane = threadIdx.x & 63, wid = threadIdx.x >> 6;
    if (lane == 0) red[wid] = ss;
    __syncthreads();
    const float total = red[0] + red[1] + red[2] + red[3];
    const float scale = expf(wls[o]) / sqrtf(total);

    // pass 2: scale + bf16 hi/lo split, 16B stores, packed layout
    const size_t rowbase = (size_t)16384 * ((size_t)g * (g + 1) / 2)
                         + (size_t)(o & 127) * kpad;
    u16* bh = bhi + rowbase;
    u16* bl = blo + rowbase;
    for (int c0 = threadIdx.x * 8; c0 < kpad; c0 += 2048) {
        short8 hv, lv;
        if (c0 + 8 <= kact) {
            f32x4 w0 = *(const f32x4*)&rowbuf[c0];
            f32x4 w1 = *(const f32x4*)&rowbuf[c0 + 4];
            float vv[8] = {w0[0], w0[1], w0[2], w0[3],
                           w1[0], w1[1], w1[2], w1[3]};
#pragma unroll
            for (int e = 0; e < 8; ++e) {
                float wn = vv[e] * scale;
                __hip_bfloat16 h = __float2bfloat16(wn);
                float hf = __bfloat162float(h);
                __hip_bfloat16 l = __float2bfloat16(wn - hf);
                hv[e] = *(short*)&h;
                lv[e] = *(short*)&l;
            }
        } else {
#pragma unroll
            for (int e = 0; e < 8; ++e) {
                const int c = c0 + e;
                float wn = (c < kact) ? rowbuf[c] * scale : 0.f;
                __hip_bfloat16 h = __float2bfloat16(wn);
                float hf = __bfloat162float(h);
                __hip_bfloat16 l = __float2bfloat16(wn - hf);
                hv[e] = *(short*)&h;
                lv[e] = *(short*)&l;
            }
        }
        *(short8*)(bh + c0) = hv;
        *(short8*)(bl + c0) = lv;
    }

    // pass 3: jac = log(diag 32 window), one thread per column
    if (threadIdx.x < 32)
        jac[(size_t)r * 1024 + (size_t)(o & 31) * 32 + threadIdx.x] =
            __logf(rowbuf[dlo + threadIdx.x] * scale);
}

// ---------------------------------------------------------------------------
// Kernel 3: y[b,o] = sum_k x[b,k]*Wn[o,k] + bias[o]  (NT GEMM, bf16x3 split)
// 128x128 tile, BK=32, 4 waves 2x2, mfma_f32_16x16x32_bf16.
//
// R9: A-DIRECT — A (X) fragments load straight from global (L1/L2) into
// ping-pong registers (even/odd unroll, static names per rule #20); only B
// goes through LDS. Rationale: R5(2blk,drain)==R8(1blk,counted)==~125us
// -> per-CU LDS throughput is the binding pipe (96KB/step). A-direct cuts
// LDS to 48KB/step (B stage 16KB + B frag reads 32KB) and moves A to the
// idle TA/L2 pipe. A-frag address pattern: per instr 16 rows x one 64B
// column window (kq lanes share a line) -> line-coalesced. LDS 32KB ->
// 2 blocks/CU again (m114 overlap). B staging split across all 4 waves.
//
// B LDS swizzle (unchanged, validated 0 conflicts R5/R6/R8):
//   slot (row, s) holds k-group s ^ ((row>>1)&3); write via pre-swizzled
//   global col-group (l&3)^((l>>3)&3); read slot = kq ^ ((fr>>1)&3).
// ---------------------------------------------------------------------------
__global__ __launch_bounds__(256, 2) void gemm_bar(
    const u16* __restrict__ xhi, const u16* __restrict__ xlo,
    const u16* __restrict__ bhi, const u16* __restrict__ blo,
    const float* __restrict__ bias, float* __restrict__ y)
{
    __shared__ __align__(16) u16 Bs_hi[2][128][32];
    __shared__ __align__(16) u16 Bs_lo[2][128][32];

    // Balanced j map: CU pair (bid, bid+256) sums to exactly 33 K-units.
    const int bid = blockIdx.x;          // 0..511
    const int jj  = bid >> 4;            // 0..31
    const int j   = (jj < 16) ? (31 - jj) : (jj - 16);
    const int i   = bid & 15;
    const int bm0 = i * 128;
    const int bn0 = j * 128;
    const int ksteps = (j + 1) * 4;      // K = (j+1)*128, BK=32; multiple of 4

    const int tid  = threadIdx.x;
    const int w    = tid >> 6;
    const int lane = tid & 63;
    const int wm   = (w & 1) * 64;       // wave's M offset in tile
    const int wn   = (w >> 1) * 64;      // wave's N offset in tile
    const int fr   = lane & 15;          // fragment row
    const int kq   = lane >> 4;          // fragment k-group (0..3)
    const int kcg  = (kq ^ ((fr >> 1) & 3)) * 8;             // swizzled read col (u16)
    const int srr  = lane >> 2;                              // staging row in 16-chunk
    const int scb  = ((lane & 3) ^ ((lane >> 3) & 3)) * 8;   // pre-swz src col (u16)

    // ---- B staging: 16 gloads/step split 4 ways (4 per wave) ----
    const size_t pbase   = (size_t)16384 * ((size_t)j * (j + 1) / 2);
    const size_t gstride = (size_t)ksteps * 32;   // packed B row length (u16)
    const u16* gsrcB = ((w >> 1) ? blo : bhi) + pbase;
    u16* ldstB = (w >> 1) ? &Bs_lo[0][0][0] : &Bs_hi[0][0][0];
    const int tbase = (w & 1) * 4;       // this wave covers t = tbase..tbase+3

#define STAGE_B(buf, kt)                                                       \
    do {                                                                       \
        const int _kb = (kt) * 32;                                             \
        u16* _dst = ldstB + (buf) * 4096;                                      \
        _Pragma("unroll")                                                      \
        for (int _u = 0; _u < 4; ++_u) {                                       \
            const int _t = tbase + _u;                                         \
            const u16* _g = gsrcB + (size_t)(_t * 16 + srr) * gstride          \
                                  + _kb + scb;                                 \
            GLOAD16(_g, _dst + _t * 512);                                      \
        }                                                                      \
    } while (0)

    // ---- A-direct: fragment base pointers (row = bm0+wm+mi*16+fr) ----
    const u16* pAh = xhi + (size_t)(bm0 + wm + fr) * IN_FEAT + kq * 8;
    const u16* pAl = xlo + (size_t)(bm0 + wm + fr) * IN_FEAT + kq * 8;

#define LOAD_A(dh, dl, kt)                                                     \
    do {                                                                       \
        const size_t _o = (size_t)(kt) * 32;                                   \
        _Pragma("unroll")                                                      \
        for (int _mi = 0; _mi < 4; ++_mi) {                                    \
            dh[_mi] = *(const short8*)(pAh + _o + (size_t)_mi * (16 * IN_FEAT));\
            dl[_mi] = *(const short8*)(pAl + _o + (size_t)_mi * (16 * IN_FEAT));\
        }                                                                      \
    } while (0)

#define COMPUTE(buf, ah, al)                                                   \
    do {                                                                       \
        const int _cb = (buf) * 4096;                                          \
        short8 bhf[4], blf[4];                                                 \
        _Pragma("unroll")                                                      \
        for (int _ni = 0; _ni < 4; ++_ni) {                                    \
            const int _row = wn + _ni * 16 + fr;                               \
            bhf[_ni] = *(const short8*)(&Bs_hi[0][0][0] + _cb + _row * 32 + kcg);\
            blf[_ni] = *(const short8*)(&Bs_lo[0][0][0] + _cb + _row * 32 + kcg);\
        }                                                                      \
        _Pragma("unroll")                                                      \
        for (int _mi = 0; _mi < 4; ++_mi)                                      \
            _Pragma("unroll")                                                  \
            for (int _ni = 0; _ni < 4; ++_ni) {                                \
                f32x4 _c = acc[_mi][_ni];                                      \
                _c = __builtin_amdgcn_mfma_f32_16x16x32_bf16(ah[_mi], bhf[_ni], _c, 0, 0, 0);\
                _c = __builtin_amdgcn_mfma_f32_16x16x32_bf16(ah[_mi], blf[_ni], _c, 0, 0, 0);\
                _c = __builtin_amdgcn_mfma_f32_16x16x32_bf16(al[_mi], bhf[_ni], _c, 0, 0, 0);\
                acc[_mi][_ni] = _c;                                            \
            }                                                                  \
    } while (0)

    f32x4 acc[4][4];
#pragma unroll
    for (int a = 0; a < 4; ++a)
#pragma unroll
        for (int b = 0; b < 4; ++b)
            acc[a][b] = (f32x4){0.f, 0.f, 0.f, 0.f};

    short8 a0h[4], a0l[4], a1h[4], a1l[4];

    // prologue: stage B(0), load A(0)
    STAGE_B(0, 0);
    LOAD_A(a0h, a0l, 0);
    __syncthreads();

    for (int kt = 0; kt < ksteps; kt += 2) {
        // even step kt: buf0, A0; prefetch (kt+1) -> buf1, A1 (always valid)
        STAGE_B(1, kt + 1);
        LOAD_A(a1h, a1l, kt + 1);
        COMPUTE(0, a0h, a0l);
        __syncthreads();

        // odd step kt+1: buf1, A1; prefetch (kt+2) -> buf0, A0 (if any)
        const bool more = (kt + 2 < ksteps);
        if (more) {
            STAGE_B(0, kt + 2);
            LOAD_A(a0h, a0l, kt + 2);
        }
        COMPUTE(1, a1h, a1l);
        if (more) __syncthreads();
    }
#undef STAGE_B
#undef LOAD_A
#undef COMPUTE

    // epilogue: C/D layout col=lane&15 (B-side n), row=(lane>>4)*4+q (A-side m)
    const int crow = (lane >> 4) * 4;
    const int ccol = lane & 15;
#pragma unroll
    for (int ni = 0; ni < 4; ++ni) {
        const int n = bn0 + wn + ni * 16 + ccol;
        const float bv = bias[n];
#pragma unroll
        for (int mi = 0; mi < 4; ++mi) {
#pragma unroll
            for (int q = 0; q < 4; ++q) {
                const int m = bm0 + wm + mi * 16 + crow + q;
                y[(size_t)m * 4096 + n] = acc[mi][ni][q] + bv;
            }
        }
    }
}

// ---------------------------------------------------------------------------
extern "C" void kernel_launch(void* const* d_in, const int* in_sizes, int n_in,
                              void* d_out, int out_size, void* d_ws, size_t ws_size,
                              hipStream_t stream)
{
    const float* x    = (const float*)d_in[0];
    const float* W    = (const float*)d_in[1];
    const float* bias = (const float*)d_in[2];
    const float* wls  = (const float*)d_in[3];
    // d_in[4], d_in[5] (masks) are not read: mask structure derived from indices.

    // workspace layout: packed-B hi/lo (2 x 16.5 MiB) + X hi/lo (2 x 16 MiB)
    const size_t need = ((size_t)BPACK * 2 + (size_t)BATCH * IN_FEAT * 2)
                        * sizeof(u16);   // 68,157,440 B
    if (ws_size < need) return;  // clean failure signal (output stays poisoned)

    u16* Bhi = (u16*)d_ws;
    u16* Blo = Bhi + (size_t)BPACK;
    u16* Xhi = Blo + (size_t)BPACK;
    u16* Xlo = Xhi + (size_t)BATCH * IN_FEAT;

    float* y   = (float*)d_out;
    float* jac = y + (size_t)BATCH * OUT_FEAT;   // 128*32*32 floats

    split_x<<<1024, 256, 0, stream>>>(x, Xhi, Xlo);
    prep_w<<<4096, 256, 0, stream>>>(W, wls, Bhi, Blo, jac);
    gemm_bar<<<512, 256, 0, stream>>>(Xhi, Xlo, Bhi, Blo, bias, y);
}